// Round 6
// baseline (313.289 us; speedup 1.0000x reference)
//
#include <hip/hip_runtime.h>
#include <stdint.h>

// GIN layer, f32 interface. bf16 MFMA GEMMs with BN-stat epilogues.
// Aggregation: bucket edges by dst>>6, cursors sliced 8-way (R5), and the
// per-bucket LDS max is now split across 2 blocks (slices 0-3 / 4-7) for
// 2x grid parallelism (R5: 782 blocks = 27% occupancy was the limiter).
// Partial maxes stored as packed bf16 with 0xFF80 (-inf) sentinel; the
// combine + feats-add is fused into gemm1's A-load (kills h0 round-trip).

#define NN 50000
#define NE 800000
#define DD 128
#define BN_EPS 1e-5f
#define NPB 1568   // padded partials stride (>= 1563 gemm blocks)
#define NB 782     // ceil(50000/64) buckets
#define NSL 8      // cursor slices per bucket
#define CAPS 256   // capacity per slice: mean 128 + 11 sigma

typedef short bf16x8 __attribute__((ext_vector_type(8)));
typedef float f32x4 __attribute__((ext_vector_type(4)));

__device__ __forceinline__ float bf2f(unsigned short u) {
    return __uint_as_float(((unsigned int)u) << 16);
}
__device__ __forceinline__ unsigned short f2bf(float f) {
    unsigned int u = __float_as_uint(f);
    u += 0x7fffu + ((u >> 16) & 1u);  // RNE
    return (unsigned short)(u >> 16);
}
__device__ __forceinline__ float plo(unsigned int p) { return bf2f((unsigned short)(p & 0xffffu)); }
__device__ __forceinline__ float phi(unsigned int p) { return bf2f((unsigned short)(p >> 16)); }
// monotone f32<->u32 encoding: order-preserving; never produces 0
__device__ __forceinline__ unsigned int encf(float f) {
    unsigned int b = __float_as_uint(f);
    return (b & 0x80000000u) ? ~b : (b | 0x80000000u);
}
__device__ __forceinline__ float decf(unsigned int e) {
    return __uint_as_float((e & 0x80000000u) ? (e ^ 0x80000000u) : ~e);
}

// ---- W1,W2 transpose -> bf16; init slice cursors ----
__global__ __launch_bounds__(256) void k_init(
    const float* __restrict__ W1, const float* __restrict__ W2,
    unsigned short* __restrict__ Wt1, unsigned short* __restrict__ Wt2,
    unsigned int* __restrict__ bcur)
{
    int g = blockIdx.x * 256 + threadIdx.x;  // 0..32767
    if (g < 16384) {
        int row = g >> 7, col = g & 127;
        Wt1[col * DD + row] = f2bf(W1[g]);
    } else {
        int h = g - 16384;
        int row = h >> 7, col = h & 127;
        Wt2[col * DD + row] = f2bf(W2[h]);
    }
    if (g < NB * NSL) bcur[g] = (unsigned int)g * CAPS;
}

// ---- feats f32 -> bf16 packed; edge append into sliced buckets ----
__global__ __launch_bounds__(256) void k_work(
    const float* __restrict__ feats, unsigned int* __restrict__ fb,
    const int* __restrict__ src, const int* __restrict__ dst,
    unsigned int* __restrict__ bcur, unsigned int* __restrict__ tmp)
{
    int g = blockIdx.x * 256 + threadIdx.x;   // 1.6M threads, 4 floats each
    float4 v = *reinterpret_cast<const float4*>(feats + (size_t)g * 4);
    uint2 o;
    o.x = (unsigned int)f2bf(v.x) | ((unsigned int)f2bf(v.y) << 16);
    o.y = (unsigned int)f2bf(v.z) | ((unsigned int)f2bf(v.w) << 16);
    *reinterpret_cast<uint2*>(fb + (size_t)g * 2) = o;
    if (g < NE) {
        int d = dst[g];
        int idx = (d >> 6) * NSL + (blockIdx.x & (NSL - 1));
        unsigned int pos = atomicAdd(&bcur[idx], 1u);
        if (pos < (unsigned int)(idx + 1) * CAPS)
            tmp[pos] = ((unsigned int)src[g] << 6) | (unsigned int)(d & 63);
    }
}

// ---- per-half-bucket LDS max -> packed bf16 partial (0xFF80 = -inf) ----
__global__ __launch_bounds__(256) void k_aggmax(
    const unsigned int* __restrict__ F,   // fb as uint rows of 64
    const unsigned int* __restrict__ tmp,
    const unsigned int* __restrict__ bcur,
    unsigned int* __restrict__ part0,
    unsigned int* __restrict__ part1)
{
    __shared__ unsigned int mx[64 * 128];  // [node][0..63]=lo, [64..127]=hi
    int tid = threadIdx.x;
    int b = blockIdx.x >> 1;
    int half = blockIdx.x & 1;
    int n0 = b * 64;
    unsigned int* __restrict__ part = half ? part1 : part0;
    for (int i = tid; i < 64 * 128; i += 256) mx[i] = 0u;  // 0 = -inf
    __syncthreads();

    int wave = tid >> 6, lane = tid & 63;
#pragma unroll 1
    for (int s = half * 4; s < half * 4 + 4; ++s) {
        int idx = b * NSL + s;
        unsigned int base = (unsigned int)idx * CAPS;
        unsigned int cnt = bcur[idx] - base;
        if (cnt > CAPS) cnt = CAPS;
        unsigned int i = wave;
        for (; i + 12 < cnt; i += 16) {
            unsigned int p0 = tmp[base + i];
            unsigned int p1 = tmp[base + i + 4];
            unsigned int p2 = tmp[base + i + 8];
            unsigned int p3 = tmp[base + i + 12];
            unsigned int u0 = F[(p0 >> 6) * 64 + lane];
            unsigned int u1 = F[(p1 >> 6) * 64 + lane];
            unsigned int u2 = F[(p2 >> 6) * 64 + lane];
            unsigned int u3 = F[(p3 >> 6) * 64 + lane];
            int d0 = (p0 & 63) << 7, d1 = (p1 & 63) << 7;
            int d2 = (p2 & 63) << 7, d3 = (p3 & 63) << 7;
            atomicMax(&mx[d0 + lane], encf(plo(u0)));
            atomicMax(&mx[d0 + 64 + lane], encf(phi(u0)));
            atomicMax(&mx[d1 + lane], encf(plo(u1)));
            atomicMax(&mx[d1 + 64 + lane], encf(phi(u1)));
            atomicMax(&mx[d2 + lane], encf(plo(u2)));
            atomicMax(&mx[d2 + 64 + lane], encf(phi(u2)));
            atomicMax(&mx[d3 + lane], encf(plo(u3)));
            atomicMax(&mx[d3 + 64 + lane], encf(phi(u3)));
        }
        for (; i < cnt; i += 4) {
            unsigned int p = tmp[base + i];
            unsigned int u = F[(p >> 6) * 64 + lane];
            int d = (p & 63) << 7;
            atomicMax(&mx[d + lane], encf(plo(u)));
            atomicMax(&mx[d + 64 + lane], encf(phi(u)));
        }
    }
    __syncthreads();

    // partial max -> packed bf16 (exact: values are bf16-representable)
    for (int idx2 = tid; idx2 < 64 * 64; idx2 += 256) {
        int node = idx2 >> 6, j = idx2 & 63;
        int n = n0 + node;
        if (n >= NN) continue;
        unsigned int e0 = mx[node * 128 + j];
        unsigned int e1 = mx[node * 128 + 64 + j];
        unsigned int lo16 = (e0 == 0u) ? 0xFF80u : (unsigned int)f2bf(decf(e0));
        unsigned int hi16 = (e1 == 0u) ? 0xFF80u : (unsigned int)f2bf(decf(e1));
        part[n * 64 + j] = lo16 | (hi16 << 16);
    }
}

// ---- GEMM: Y = act(X) @ W + b (bf16 MFMA) + per-column sum/sumsq ----
// MODE 1: A = relu(pa[k]*x + pc[k])        (layer-2: BN1+ReLU on load)
// MODE 2: A = fb + max0(max(part0,part1))  (layer-1: agg combine on load)
// block = 256 thr; 32 rows; wave = 16 rows x 64 cols.
// mfma_f32_16x16x32_bf16: A[m=lane&15][k=quad*8+j], B[n=lane&15][k=quad*8+j],
// C/D: col=lane&15, row=quad*4+reg (m89-verified).
template <int MODE>
__global__ __launch_bounds__(256) void k_gemm(
    const unsigned short* __restrict__ X, const unsigned int* __restrict__ fbp,
    const unsigned int* __restrict__ p0, const unsigned int* __restrict__ p1,
    const unsigned short* __restrict__ Wt, const float* __restrict__ bias,
    const float* __restrict__ pa, const float* __restrict__ pc,
    unsigned short* __restrict__ Y, float* __restrict__ partials)
{
    __shared__ float lsum[128], lsq[128];
    int tid = threadIdx.x;
    if (tid < 128) { lsum[tid] = 0.f; lsq[tid] = 0.f; }
    __syncthreads();
    int wave = tid >> 6, lane = tid & 63;
    int quad = lane >> 4, l16 = lane & 15;
    int m0 = blockIdx.x * 32 + (wave >> 1) * 16;
    int nh = (wave & 1) * 64;
    int myrow = m0 + l16;
    int kq = quad * 8;

    f32x4 acc[4];
#pragma unroll
    for (int j = 0; j < 4; ++j)
#pragma unroll
        for (int r = 0; r < 4; ++r) acc[j][r] = 0.f;

#pragma unroll
    for (int k0 = 0; k0 < 128; k0 += 32) {
        bf16x8 a;
        if (myrow < NN) {
            if (MODE == 2) {
                int uoff = myrow * 64 + ((k0 + kq) >> 1);
                uint4 xv = *reinterpret_cast<const uint4*>(fbp + uoff);
                uint4 q0 = *reinterpret_cast<const uint4*>(p0 + uoff);
                uint4 q1 = *reinterpret_cast<const uint4*>(p1 + uoff);
                unsigned int xs[4] = {xv.x, xv.y, xv.z, xv.w};
                unsigned int a0[4] = {q0.x, q0.y, q0.z, q0.w};
                unsigned int a1[4] = {q1.x, q1.y, q1.z, q1.w};
#pragma unroll
                for (int t = 0; t < 4; ++t) {
                    float mlo = fmaxf(plo(a0[t]), plo(a1[t]));
                    float mhi = fmaxf(phi(a0[t]), phi(a1[t]));
                    if (mlo < -3.0e38f) mlo = 0.f;   // both -inf: no in-edges
                    if (mhi < -3.0e38f) mhi = 0.f;
                    a[2 * t] = (short)f2bf(plo(xs[t]) + mlo);
                    a[2 * t + 1] = (short)f2bf(phi(xs[t]) + mhi);
                }
            } else {
                a = *reinterpret_cast<const bf16x8*>(X + myrow * DD + k0 + kq);
                float4 av0 = *reinterpret_cast<const float4*>(pa + k0 + kq);
                float4 av1 = *reinterpret_cast<const float4*>(pa + k0 + kq + 4);
                float4 cv0 = *reinterpret_cast<const float4*>(pc + k0 + kq);
                float4 cv1 = *reinterpret_cast<const float4*>(pc + k0 + kq + 4);
                float fa[8] = {av0.x, av0.y, av0.z, av0.w, av1.x, av1.y, av1.z, av1.w};
                float fc[8] = {cv0.x, cv0.y, cv0.z, cv0.w, cv1.x, cv1.y, cv1.z, cv1.w};
#pragma unroll
                for (int j = 0; j < 8; ++j) {
                    float v = fmaxf(fa[j] * bf2f((unsigned short)a[j]) + fc[j], 0.f);
                    a[j] = (short)f2bf(v);
                }
            }
        } else {
#pragma unroll
            for (int j = 0; j < 8; ++j) a[j] = 0;
        }
#pragma unroll
        for (int j = 0; j < 4; ++j) {
            bf16x8 bb = *reinterpret_cast<const bf16x8*>(Wt + (nh + j * 16 + l16) * DD + k0 + kq);
            acc[j] = __builtin_amdgcn_mfma_f32_16x16x32_bf16(a, bb, acc[j], 0, 0, 0);
        }
    }

    int rbase = m0 + quad * 4;
#pragma unroll
    for (int j = 0; j < 4; ++j) {
        int col = nh + j * 16 + l16;
        float bcol = bias[col];
        float s = 0.f, q = 0.f;
#pragma unroll
        for (int r = 0; r < 4; ++r) {
            int row = rbase + r;
            if (row < NN) {
                float v = acc[j][r] + bcol;
                Y[row * DD + col] = f2bf(v);
                s += v;
                q += v * v;
            }
        }
        s += __shfl_xor(s, 16, 64);
        s += __shfl_xor(s, 32, 64);
        q += __shfl_xor(q, 16, 64);
        q += __shfl_xor(q, 32, 64);
        if (quad == 0) {
            atomicAdd(&lsum[col], s);
            atomicAdd(&lsq[col], q);
        }
    }
    __syncthreads();
    if (tid < 128) {
        partials[tid * NPB + blockIdx.x] = lsum[tid];
        partials[(128 + tid) * NPB + blockIdx.x] = lsq[tid];
    }
}

// ---- reduce partials + BN affine: a = g*rsqrt(var+eps), c = be - mean*a ----
__global__ void k_redparams(const float* __restrict__ partials, int nblk,
                            const float* __restrict__ g, const float* __restrict__ be,
                            float* __restrict__ a, float* __restrict__ c) {
    __shared__ float ls[256], lq[256];
    int t = threadIdx.x;
    int col = blockIdx.x;  // 0..127
    float s = 0.f, q = 0.f;
    for (int i = t; i < nblk; i += 256) {
        s += partials[col * NPB + i];
        q += partials[(128 + col) * NPB + i];
    }
    ls[t] = s; lq[t] = q;
    __syncthreads();
    for (int off = 128; off > 0; off >>= 1) {
        if (t < off) { ls[t] += ls[t + off]; lq[t] += lq[t + off]; }
        __syncthreads();
    }
    if (t == 0) {
        float mean = ls[0] / (float)NN;
        float var = fmaxf(lq[0] / (float)NN - mean * mean, 0.f);
        float av = g[col] * rsqrtf(var + BN_EPS);
        a[col] = av;
        c[col] = be[col] - mean * av;
    }
}

// ---- stats of z = relu(a2*Y2 + c2) ----
__global__ __launch_bounds__(256) void k_zstats(
    const unsigned short* __restrict__ Y2, const float* __restrict__ a2,
    const float* __restrict__ c2, float* __restrict__ partials)
{
    __shared__ float ls[256], lq[256];
    int t = threadIdx.x;
    int col = t & 127, half = t >> 7;
    float av = a2[col], cv = c2[col];
    float s = 0.f, q = 0.f;
    for (int row = blockIdx.x * 2 + half; row < NN; row += gridDim.x * 2) {
        float z = fmaxf(av * bf2f(Y2[row * DD + col]) + cv, 0.f);
        s += z;
        q += z * z;
    }
    ls[t] = s;
    lq[t] = q;
    __syncthreads();
    if (t < 128) {
        partials[t * NPB + blockIdx.x] = ls[t] + ls[t + 128];
        partials[(128 + t) * NPB + blockIdx.x] = lq[t] + lq[t + 128];
    }
}

// ---- out = a3*relu(a2*Y2+c2) + c3, f32 out ----
__global__ __launch_bounds__(256) void k_out(
    const unsigned short* __restrict__ Y2, const float* __restrict__ a2,
    const float* __restrict__ c2, const float* __restrict__ a3,
    const float* __restrict__ c3, float* __restrict__ out)
{
    int g = blockIdx.x * 256 + threadIdx.x;
    int base = g * 4;
    int c0 = base & 127;
    uint2 p = *reinterpret_cast<const uint2*>(Y2 + base);
    float4 av2 = *reinterpret_cast<const float4*>(a2 + c0);
    float4 cv2 = *reinterpret_cast<const float4*>(c2 + c0);
    float4 av3 = *reinterpret_cast<const float4*>(a3 + c0);
    float4 cv3 = *reinterpret_cast<const float4*>(c3 + c0);
    float z0 = fmaxf(av2.x * plo(p.x) + cv2.x, 0.f);
    float z1 = fmaxf(av2.y * phi(p.x) + cv2.y, 0.f);
    float z2 = fmaxf(av2.z * plo(p.y) + cv2.z, 0.f);
    float z3 = fmaxf(av2.w * phi(p.y) + cv2.w, 0.f);
    float4 o;
    o.x = av3.x * z0 + cv3.x;
    o.y = av3.y * z1 + cv3.y;
    o.z = av3.z * z2 + cv3.z;
    o.w = av3.w * z3 + cv3.w;
    *reinterpret_cast<float4*>(out + base) = o;
}

extern "C" void kernel_launch(void* const* d_in, const int* in_sizes, int n_in,
                              void* d_out, int out_size, void* d_ws, size_t ws_size,
                              hipStream_t stream) {
    (void)in_sizes; (void)n_in; (void)out_size; (void)ws_size;
    const float* feats = (const float*)d_in[0];
    const int* src = (const int*)d_in[1];
    const int* dst = (const int*)d_in[2];
    const float* W1 = (const float*)d_in[3];
    const float* b1 = (const float*)d_in[4];
    const float* g1 = (const float*)d_in[5];
    const float* be1 = (const float*)d_in[6];
    const float* W2 = (const float*)d_in[7];
    const float* b2 = (const float*)d_in[8];
    const float* g2 = (const float*)d_in[9];
    const float* be2 = (const float*)d_in[10];
    const float* g3 = (const float*)d_in[11];
    const float* be3 = (const float*)d_in[12];
    float* out = (float*)d_out;

    char* p = (char*)d_ws;
    auto alloc = [&](size_t n) { char* r = p; p += (n + 255) & ~(size_t)255; return r; };
    unsigned int* fb = (unsigned int*)alloc((size_t)NN * 64 * 4);      // packed bf16
    unsigned int* part0 = (unsigned int*)alloc((size_t)NN * 64 * 4);   // packed bf16
    unsigned int* part1 = (unsigned int*)alloc((size_t)NN * 64 * 4);   // packed bf16
    unsigned int* bcur = (unsigned int*)alloc((size_t)NB * NSL * 4);
    unsigned int* tmp = (unsigned int*)alloc((size_t)NB * NSL * CAPS * 4);
    unsigned short* Y1 = (unsigned short*)alloc((size_t)NN * DD * 2);
    unsigned short* Y2 = (unsigned short*)alloc((size_t)NN * DD * 2);
    unsigned short* Wt1 = (unsigned short*)alloc((size_t)DD * DD * 2);
    unsigned short* Wt2 = (unsigned short*)alloc((size_t)DD * DD * 2);
    float* partials = (float*)alloc((size_t)256 * NPB * 4);
    float* a1 = (float*)alloc(DD * 4); float* c1 = (float*)alloc(DD * 4);
    float* a2 = (float*)alloc(DD * 4); float* c2 = (float*)alloc(DD * 4);
    float* a3 = (float*)alloc(DD * 4); float* c3 = (float*)alloc(DD * 4);

    k_init<<<128, 256, 0, stream>>>(W1, W2, Wt1, Wt2, bcur);
    k_work<<<6250, 256, 0, stream>>>(feats, fb, src, dst, bcur, tmp);
    k_aggmax<<<NB * 2, 256, 0, stream>>>(fb, tmp, bcur, part0, part1);
    // layer 1 (agg combine + feats add fused into A-load)
    k_gemm<2><<<1563, 256, 0, stream>>>(nullptr, fb, part0, part1, Wt1, b1,
                                        nullptr, nullptr, Y1, partials);
    k_redparams<<<128, 256, 0, stream>>>(partials, 1563, g1, be1, a1, c1);
    // layer 2 (BN1+ReLU fused into A-load)
    k_gemm<1><<<1563, 256, 0, stream>>>(Y1, nullptr, nullptr, nullptr, Wt2, b2,
                                        a1, c1, Y2, partials);
    k_redparams<<<128, 256, 0, stream>>>(partials, 1563, g2, be2, a2, c2);
    // outer BN over z = relu(a2*Y2+c2)
    k_zstats<<<256, 256, 0, stream>>>(Y2, a2, c2, partials);
    k_redparams<<<128, 256, 0, stream>>>(partials, 256, g3, be3, a3, c3);
    k_out<<<6250, 256, 0, stream>>>(Y2, a2, c2, a3, c3, out);
}

// Round 7
// 285.322 us; speedup vs baseline: 1.0980x; 1.0980x over previous
//
#include <hip/hip_runtime.h>
#include <stdint.h>

// GIN layer, f32 interface. bf16 MFMA GEMMs with BN-stat epilogues.
// Aggregation: bucket edges by dst>>5 (1563 buckets x 32 nodes), cursors
// sliced 8-way at append; one WAVE per slice in aggmax. Edge words are
// loaded lane-parallel (1 coalesced load / 64 edges) and broadcast via
// __shfl, so the row-gathers issue back-to-back (8 in flight) instead of
// straddling a dependent tmp-load (R6: 54 cyc/edge, MLP-bound).
// Partial maxes: packed bf16, 0xFF80 = -inf sentinel; combine + feats-add
// fused into gemm1's A-load.

#define NN 50000
#define NE 800000
#define DD 128
#define BN_EPS 1e-5f
#define NPB 1568   // padded partials stride (>= 1563 gemm blocks)
#define NB 1563    // ceil(50000/32) buckets (32 dst nodes each)
#define NSL 8      // cursor slices per bucket
#define CAPS 128   // capacity per slice: mean 64 + 8 sigma

typedef short bf16x8 __attribute__((ext_vector_type(8)));
typedef float f32x4 __attribute__((ext_vector_type(4)));

__device__ __forceinline__ float bf2f(unsigned short u) {
    return __uint_as_float(((unsigned int)u) << 16);
}
__device__ __forceinline__ unsigned short f2bf(float f) {
    unsigned int u = __float_as_uint(f);
    u += 0x7fffu + ((u >> 16) & 1u);  // RNE
    return (unsigned short)(u >> 16);
}
__device__ __forceinline__ float plo(unsigned int p) { return bf2f((unsigned short)(p & 0xffffu)); }
__device__ __forceinline__ float phi(unsigned int p) { return bf2f((unsigned short)(p >> 16)); }
// monotone f32<->u32 encoding: order-preserving; never produces 0
__device__ __forceinline__ unsigned int encf(float f) {
    unsigned int b = __float_as_uint(f);
    return (b & 0x80000000u) ? ~b : (b | 0x80000000u);
}
__device__ __forceinline__ float decf(unsigned int e) {
    return __uint_as_float((e & 0x80000000u) ? (e ^ 0x80000000u) : ~e);
}

// ---- W1,W2 transpose -> bf16; init slice cursors ----
__global__ __launch_bounds__(256) void k_init(
    const float* __restrict__ W1, const float* __restrict__ W2,
    unsigned short* __restrict__ Wt1, unsigned short* __restrict__ Wt2,
    unsigned int* __restrict__ bcur)
{
    int g = blockIdx.x * 256 + threadIdx.x;  // 0..32767
    if (g < 16384) {
        int row = g >> 7, col = g & 127;
        Wt1[col * DD + row] = f2bf(W1[g]);
    } else {
        int h = g - 16384;
        int row = h >> 7, col = h & 127;
        Wt2[col * DD + row] = f2bf(W2[h]);
    }
    if (g < NB * NSL) bcur[g] = (unsigned int)g * CAPS;
}

// ---- feats f32 -> bf16 packed; edge append into sliced buckets ----
__global__ __launch_bounds__(256) void k_work(
    const float* __restrict__ feats, unsigned int* __restrict__ fb,
    const int* __restrict__ src, const int* __restrict__ dst,
    unsigned int* __restrict__ bcur, unsigned int* __restrict__ tmp)
{
    int g = blockIdx.x * 256 + threadIdx.x;   // 1.6M threads, 4 floats each
    float4 v = *reinterpret_cast<const float4*>(feats + (size_t)g * 4);
    uint2 o;
    o.x = (unsigned int)f2bf(v.x) | ((unsigned int)f2bf(v.y) << 16);
    o.y = (unsigned int)f2bf(v.z) | ((unsigned int)f2bf(v.w) << 16);
    *reinterpret_cast<uint2*>(fb + (size_t)g * 2) = o;
    if (g < NE) {
        int d = dst[g];
        int idx = (d >> 5) * NSL + (blockIdx.x & (NSL - 1));
        unsigned int pos = atomicAdd(&bcur[idx], 1u);
        if (pos < (unsigned int)(idx + 1) * CAPS)
            tmp[pos] = ((unsigned int)src[g] << 5) | (unsigned int)(d & 31);
    }
}

// ---- per-half-bucket LDS max -> packed bf16 partial (0xFF80 = -inf) ----
// grid = NB*2; block b,half; wave w owns slice half*4+w entirely.
__global__ __launch_bounds__(256) void k_aggmax(
    const unsigned int* __restrict__ F,   // fb as uint rows of 64
    const unsigned int* __restrict__ tmp,
    const unsigned int* __restrict__ bcur,
    unsigned int* __restrict__ part0,
    unsigned int* __restrict__ part1)
{
    __shared__ unsigned int mx[32 * 128];  // [node][0..63]=lo, [64..127]=hi
    int tid = threadIdx.x;
    int b = blockIdx.x >> 1;
    int half = blockIdx.x & 1;
    int n0 = b * 32;
    unsigned int* __restrict__ part = half ? part1 : part0;
    for (int i = tid; i < 32 * 128; i += 256) mx[i] = 0u;  // 0 = -inf
    __syncthreads();

    int wave = tid >> 6, lane = tid & 63;
    int widx = b * NSL + half * 4 + wave;     // this wave's slice
    unsigned int base = (unsigned int)widx * CAPS;
    unsigned int cnt = bcur[widx] - base;
    if (cnt > CAPS) cnt = CAPS;

    for (unsigned int chunk = 0; chunk < cnt; chunk += 64) {
        int nw = (int)(cnt - chunk) < 64 ? (int)(cnt - chunk) : 64;
        unsigned int pw = (lane < nw) ? tmp[base + chunk + lane] : 0u;
        int j = 0;
        for (; j + 8 <= nw; j += 8) {
            unsigned int e0 = __shfl(pw, j + 0);
            unsigned int e1 = __shfl(pw, j + 1);
            unsigned int e2 = __shfl(pw, j + 2);
            unsigned int e3 = __shfl(pw, j + 3);
            unsigned int e4 = __shfl(pw, j + 4);
            unsigned int e5 = __shfl(pw, j + 5);
            unsigned int e6 = __shfl(pw, j + 6);
            unsigned int e7 = __shfl(pw, j + 7);
            unsigned int u0 = F[(e0 >> 5) * 64 + lane];
            unsigned int u1 = F[(e1 >> 5) * 64 + lane];
            unsigned int u2 = F[(e2 >> 5) * 64 + lane];
            unsigned int u3 = F[(e3 >> 5) * 64 + lane];
            unsigned int u4 = F[(e4 >> 5) * 64 + lane];
            unsigned int u5 = F[(e5 >> 5) * 64 + lane];
            unsigned int u6 = F[(e6 >> 5) * 64 + lane];
            unsigned int u7 = F[(e7 >> 5) * 64 + lane];
            int d0 = (e0 & 31) << 7, d1 = (e1 & 31) << 7;
            int d2 = (e2 & 31) << 7, d3 = (e3 & 31) << 7;
            int d4 = (e4 & 31) << 7, d5 = (e5 & 31) << 7;
            int d6 = (e6 & 31) << 7, d7 = (e7 & 31) << 7;
            atomicMax(&mx[d0 + lane], encf(plo(u0)));
            atomicMax(&mx[d0 + 64 + lane], encf(phi(u0)));
            atomicMax(&mx[d1 + lane], encf(plo(u1)));
            atomicMax(&mx[d1 + 64 + lane], encf(phi(u1)));
            atomicMax(&mx[d2 + lane], encf(plo(u2)));
            atomicMax(&mx[d2 + 64 + lane], encf(phi(u2)));
            atomicMax(&mx[d3 + lane], encf(plo(u3)));
            atomicMax(&mx[d3 + 64 + lane], encf(phi(u3)));
            atomicMax(&mx[d4 + lane], encf(plo(u4)));
            atomicMax(&mx[d4 + 64 + lane], encf(phi(u4)));
            atomicMax(&mx[d5 + lane], encf(plo(u5)));
            atomicMax(&mx[d5 + 64 + lane], encf(phi(u5)));
            atomicMax(&mx[d6 + lane], encf(plo(u6)));
            atomicMax(&mx[d6 + 64 + lane], encf(phi(u6)));
            atomicMax(&mx[d7 + lane], encf(plo(u7)));
            atomicMax(&mx[d7 + 64 + lane], encf(phi(u7)));
        }
        for (; j < nw; ++j) {
            unsigned int e = __shfl(pw, j);
            unsigned int u = F[(e >> 5) * 64 + lane];
            int d = (e & 31) << 7;
            atomicMax(&mx[d + lane], encf(plo(u)));
            atomicMax(&mx[d + 64 + lane], encf(phi(u)));
        }
    }
    __syncthreads();

    // partial max -> packed bf16 (exact: values are bf16-representable)
    for (int idx2 = tid; idx2 < 32 * 64; idx2 += 256) {
        int node = idx2 >> 6, j = idx2 & 63;
        int n = n0 + node;
        if (n >= NN) continue;
        unsigned int e0 = mx[node * 128 + j];
        unsigned int e1 = mx[node * 128 + 64 + j];
        unsigned int lo16 = (e0 == 0u) ? 0xFF80u : (unsigned int)f2bf(decf(e0));
        unsigned int hi16 = (e1 == 0u) ? 0xFF80u : (unsigned int)f2bf(decf(e1));
        part[n * 64 + j] = lo16 | (hi16 << 16);
    }
}

// ---- GEMM: Y = act(X) @ W + b (bf16 MFMA) + per-column sum/sumsq ----
// MODE 1: A = relu(pa[k]*x + pc[k])        (layer-2: BN1+ReLU on load)
// MODE 2: A = fb + max0(max(part0,part1))  (layer-1: agg combine on load)
// block = 256 thr; 32 rows; wave = 16 rows x 64 cols.
// mfma_f32_16x16x32_bf16: A[m=lane&15][k=quad*8+j], B[n=lane&15][k=quad*8+j],
// C/D: col=lane&15, row=quad*4+reg (m89-verified).
template <int MODE>
__global__ __launch_bounds__(256) void k_gemm(
    const unsigned short* __restrict__ X, const unsigned int* __restrict__ fbp,
    const unsigned int* __restrict__ p0, const unsigned int* __restrict__ p1,
    const unsigned short* __restrict__ Wt, const float* __restrict__ bias,
    const float* __restrict__ pa, const float* __restrict__ pc,
    unsigned short* __restrict__ Y, float* __restrict__ partials)
{
    __shared__ float lsum[128], lsq[128];
    int tid = threadIdx.x;
    if (tid < 128) { lsum[tid] = 0.f; lsq[tid] = 0.f; }
    __syncthreads();
    int wave = tid >> 6, lane = tid & 63;
    int quad = lane >> 4, l16 = lane & 15;
    int m0 = blockIdx.x * 32 + (wave >> 1) * 16;
    int nh = (wave & 1) * 64;
    int myrow = m0 + l16;
    int kq = quad * 8;

    f32x4 acc[4];
#pragma unroll
    for (int j = 0; j < 4; ++j)
#pragma unroll
        for (int r = 0; r < 4; ++r) acc[j][r] = 0.f;

#pragma unroll
    for (int k0 = 0; k0 < 128; k0 += 32) {
        bf16x8 a;
        if (myrow < NN) {
            if (MODE == 2) {
                int uoff = myrow * 64 + ((k0 + kq) >> 1);
                uint4 xv = *reinterpret_cast<const uint4*>(fbp + uoff);
                uint4 q0 = *reinterpret_cast<const uint4*>(p0 + uoff);
                uint4 q1 = *reinterpret_cast<const uint4*>(p1 + uoff);
                unsigned int xs[4] = {xv.x, xv.y, xv.z, xv.w};
                unsigned int a0[4] = {q0.x, q0.y, q0.z, q0.w};
                unsigned int a1[4] = {q1.x, q1.y, q1.z, q1.w};
#pragma unroll
                for (int t = 0; t < 4; ++t) {
                    float mlo = fmaxf(plo(a0[t]), plo(a1[t]));
                    float mhi = fmaxf(phi(a0[t]), phi(a1[t]));
                    if (mlo < -3.0e38f) mlo = 0.f;   // both -inf: no in-edges
                    if (mhi < -3.0e38f) mhi = 0.f;
                    a[2 * t] = (short)f2bf(plo(xs[t]) + mlo);
                    a[2 * t + 1] = (short)f2bf(phi(xs[t]) + mhi);
                }
            } else {
                a = *reinterpret_cast<const bf16x8*>(X + myrow * DD + k0 + kq);
                float4 av0 = *reinterpret_cast<const float4*>(pa + k0 + kq);
                float4 av1 = *reinterpret_cast<const float4*>(pa + k0 + kq + 4);
                float4 cv0 = *reinterpret_cast<const float4*>(pc + k0 + kq);
                float4 cv1 = *reinterpret_cast<const float4*>(pc + k0 + kq + 4);
                float fa[8] = {av0.x, av0.y, av0.z, av0.w, av1.x, av1.y, av1.z, av1.w};
                float fc[8] = {cv0.x, cv0.y, cv0.z, cv0.w, cv1.x, cv1.y, cv1.z, cv1.w};
#pragma unroll
                for (int j = 0; j < 8; ++j) {
                    float v = fmaxf(fa[j] * bf2f((unsigned short)a[j]) + fc[j], 0.f);
                    a[j] = (short)f2bf(v);
                }
            }
        } else {
#pragma unroll
            for (int j = 0; j < 8; ++j) a[j] = 0;
        }
#pragma unroll
        for (int j = 0; j < 4; ++j) {
            bf16x8 bb = *reinterpret_cast<const bf16x8*>(Wt + (nh + j * 16 + l16) * DD + k0 + kq);
            acc[j] = __builtin_amdgcn_mfma_f32_16x16x32_bf16(a, bb, acc[j], 0, 0, 0);
        }
    }

    int rbase = m0 + quad * 4;
#pragma unroll
    for (int j = 0; j < 4; ++j) {
        int col = nh + j * 16 + l16;
        float bcol = bias[col];
        float s = 0.f, q = 0.f;
#pragma unroll
        for (int r = 0; r < 4; ++r) {
            int row = rbase + r;
            if (row < NN) {
                float v = acc[j][r] + bcol;
                Y[row * DD + col] = f2bf(v);
                s += v;
                q += v * v;
            }
        }
        s += __shfl_xor(s, 16, 64);
        s += __shfl_xor(s, 32, 64);
        q += __shfl_xor(q, 16, 64);
        q += __shfl_xor(q, 32, 64);
        if (quad == 0) {
            atomicAdd(&lsum[col], s);
            atomicAdd(&lsq[col], q);
        }
    }
    __syncthreads();
    if (tid < 128) {
        partials[tid * NPB + blockIdx.x] = lsum[tid];
        partials[(128 + tid) * NPB + blockIdx.x] = lsq[tid];
    }
}

// ---- reduce partials + BN affine: a = g*rsqrt(var+eps), c = be - mean*a ----
__global__ void k_redparams(const float* __restrict__ partials, int nblk,
                            const float* __restrict__ g, const float* __restrict__ be,
                            float* __restrict__ a, float* __restrict__ c) {
    __shared__ float ls[256], lq[256];
    int t = threadIdx.x;
    int col = blockIdx.x;  // 0..127
    float s = 0.f, q = 0.f;
    for (int i = t; i < nblk; i += 256) {
        s += partials[col * NPB + i];
        q += partials[(128 + col) * NPB + i];
    }
    ls[t] = s; lq[t] = q;
    __syncthreads();
    for (int off = 128; off > 0; off >>= 1) {
        if (t < off) { ls[t] += ls[t + off]; lq[t] += lq[t + off]; }
        __syncthreads();
    }
    if (t == 0) {
        float mean = ls[0] / (float)NN;
        float var = fmaxf(lq[0] / (float)NN - mean * mean, 0.f);
        float av = g[col] * rsqrtf(var + BN_EPS);
        a[col] = av;
        c[col] = be[col] - mean * av;
    }
}

// ---- stats of z = relu(a2*Y2 + c2) ----
__global__ __launch_bounds__(256) void k_zstats(
    const unsigned short* __restrict__ Y2, const float* __restrict__ a2,
    const float* __restrict__ c2, float* __restrict__ partials)
{
    __shared__ float ls[256], lq[256];
    int t = threadIdx.x;
    int col = t & 127, half = t >> 7;
    float av = a2[col], cv = c2[col];
    float s = 0.f, q = 0.f;
    for (int row = blockIdx.x * 2 + half; row < NN; row += gridDim.x * 2) {
        float z = fmaxf(av * bf2f(Y2[row * DD + col]) + cv, 0.f);
        s += z;
        q += z * z;
    }
    ls[t] = s;
    lq[t] = q;
    __syncthreads();
    if (t < 128) {
        partials[t * NPB + blockIdx.x] = ls[t] + ls[t + 128];
        partials[(128 + t) * NPB + blockIdx.x] = lq[t] + lq[t + 128];
    }
}

// ---- out = a3*relu(a2*Y2+c2) + c3, f32 out ----
__global__ __launch_bounds__(256) void k_out(
    const unsigned short* __restrict__ Y2, const float* __restrict__ a2,
    const float* __restrict__ c2, const float* __restrict__ a3,
    const float* __restrict__ c3, float* __restrict__ out)
{
    int g = blockIdx.x * 256 + threadIdx.x;
    int base = g * 4;
    int c0 = base & 127;
    uint2 p = *reinterpret_cast<const uint2*>(Y2 + base);
    float4 av2 = *reinterpret_cast<const float4*>(a2 + c0);
    float4 cv2 = *reinterpret_cast<const float4*>(c2 + c0);
    float4 av3 = *reinterpret_cast<const float4*>(a3 + c0);
    float4 cv3 = *reinterpret_cast<const float4*>(c3 + c0);
    float z0 = fmaxf(av2.x * plo(p.x) + cv2.x, 0.f);
    float z1 = fmaxf(av2.y * phi(p.x) + cv2.y, 0.f);
    float z2 = fmaxf(av2.z * plo(p.y) + cv2.z, 0.f);
    float z3 = fmaxf(av2.w * phi(p.y) + cv2.w, 0.f);
    float4 o;
    o.x = av3.x * z0 + cv3.x;
    o.y = av3.y * z1 + cv3.y;
    o.z = av3.z * z2 + cv3.z;
    o.w = av3.w * z3 + cv3.w;
    *reinterpret_cast<float4*>(out + base) = o;
}

extern "C" void kernel_launch(void* const* d_in, const int* in_sizes, int n_in,
                              void* d_out, int out_size, void* d_ws, size_t ws_size,
                              hipStream_t stream) {
    (void)in_sizes; (void)n_in; (void)out_size; (void)ws_size;
    const float* feats = (const float*)d_in[0];
    const int* src = (const int*)d_in[1];
    const int* dst = (const int*)d_in[2];
    const float* W1 = (const float*)d_in[3];
    const float* b1 = (const float*)d_in[4];
    const float* g1 = (const float*)d_in[5];
    const float* be1 = (const float*)d_in[6];
    const float* W2 = (const float*)d_in[7];
    const float* b2 = (const float*)d_in[8];
    const float* g2 = (const float*)d_in[9];
    const float* be2 = (const float*)d_in[10];
    const float* g3 = (const float*)d_in[11];
    const float* be3 = (const float*)d_in[12];
    float* out = (float*)d_out;

    char* p = (char*)d_ws;
    auto alloc = [&](size_t n) { char* r = p; p += (n + 255) & ~(size_t)255; return r; };
    unsigned int* fb = (unsigned int*)alloc((size_t)NN * 64 * 4);      // packed bf16
    unsigned int* part0 = (unsigned int*)alloc((size_t)NN * 64 * 4);   // packed bf16
    unsigned int* part1 = (unsigned int*)alloc((size_t)NN * 64 * 4);   // packed bf16
    unsigned int* bcur = (unsigned int*)alloc((size_t)NB * NSL * 4);
    unsigned int* tmp = (unsigned int*)alloc((size_t)NB * NSL * CAPS * 4);
    unsigned short* Y1 = (unsigned short*)alloc((size_t)NN * DD * 2);
    unsigned short* Y2 = (unsigned short*)alloc((size_t)NN * DD * 2);
    unsigned short* Wt1 = (unsigned short*)alloc((size_t)DD * DD * 2);
    unsigned short* Wt2 = (unsigned short*)alloc((size_t)DD * DD * 2);
    float* partials = (float*)alloc((size_t)256 * NPB * 4);
    float* a1 = (float*)alloc(DD * 4); float* c1 = (float*)alloc(DD * 4);
    float* a2 = (float*)alloc(DD * 4); float* c2 = (float*)alloc(DD * 4);
    float* a3 = (float*)alloc(DD * 4); float* c3 = (float*)alloc(DD * 4);

    k_init<<<128, 256, 0, stream>>>(W1, W2, Wt1, Wt2, bcur);
    k_work<<<6250, 256, 0, stream>>>(feats, fb, src, dst, bcur, tmp);
    k_aggmax<<<NB * 2, 256, 0, stream>>>(fb, tmp, bcur, part0, part1);
    // layer 1 (agg combine + feats add fused into A-load)
    k_gemm<2><<<1563, 256, 0, stream>>>(nullptr, fb, part0, part1, Wt1, b1,
                                        nullptr, nullptr, Y1, partials);
    k_redparams<<<128, 256, 0, stream>>>(partials, 1563, g1, be1, a1, c1);
    // layer 2 (BN1+ReLU fused into A-load)
    k_gemm<1><<<1563, 256, 0, stream>>>(Y1, nullptr, nullptr, nullptr, Wt2, b2,
                                        a1, c1, Y2, partials);
    k_redparams<<<128, 256, 0, stream>>>(partials, 1563, g2, be2, a2, c2);
    // outer BN over z = relu(a2*Y2+c2)
    k_zstats<<<256, 256, 0, stream>>>(Y2, a2, c2, partials);
    k_redparams<<<128, 256, 0, stream>>>(partials, 256, g3, be3, a3, c3);
    k_out<<<6250, 256, 0, stream>>>(Y2, a2, c2, a3, c3, out);
}